// Round 4
// baseline (4213.277 us; speedup 1.0000x reference)
//
#include <hip/hip_runtime.h>
#include <hip/hip_bf16.h>

// Problem constants (fixed shapes per reference setup_inputs; n_step = 200).
#define MM 64
#define NN 4096
#define KK 4096
#define NSTEP 200

typedef __bf16 bf16x8 __attribute__((ext_vector_type(8)));
typedef float  f32x4  __attribute__((ext_vector_type(4)));

static __device__ __forceinline__ unsigned short f2bf(float f) {
    __hip_bfloat16 h = __float2bfloat16(f);
    return __builtin_bit_cast(unsigned short, h);
}
static __device__ __forceinline__ float bf2f(unsigned short u) {
    __hip_bfloat16 h = __builtin_bit_cast(__hip_bfloat16, u);
    return __bfloat162float(h);
}

// Fragment layouts (mfma_f32_16x16x32_bf16, m89 mapping:
//   frag[lane=q*16+l16][j] = Mat[row16=l16][k=q*8+j]):
// A (g):  addr(m,kg) = ((kc*4 + (m>>4))*64 + q*16 + (m&15))*8 + j
// B (W):  addr(n,kg) = (((n>>4)*128 + kc)*64 + q*16 + (n&15))*8 + j
//   (identical to the 3818us baseline layout: old (s*8+ns) == n>>4)

// ---------------------------------------------------------------------------
// Prologue 1: s = 0.5*(W[n][k]+W[k][n]), diag zero; (hi,lo) bf16 split,
// scattered into B-fragment order. 64x64 tiles, LDS transpose.
// ---------------------------------------------------------------------------
__global__ __launch_bounds__(256) void symm_kernel(const float* __restrict__ W,
                                                   unsigned short* __restrict__ Wfh,
                                                   unsigned short* __restrict__ Wfl) {
    __shared__ float T[64][65];
    const int tid = threadIdx.x;
    const int r0 = blockIdx.y * 64, c0 = blockIdx.x * 64;
#pragma unroll
    for (int i = 0; i < 4; ++i) {
        int lin = tid + i * 256;
        int cc  = lin >> 4;
        int r4  = (lin & 15) * 4;
        float4 v = *(const float4*)&W[(size_t)(c0 + cc) * NN + r0 + r4];
        T[cc][r4 + 0] = v.x; T[cc][r4 + 1] = v.y;
        T[cc][r4 + 2] = v.z; T[cc][r4 + 3] = v.w;
    }
    __syncthreads();
#pragma unroll
    for (int i = 0; i < 4; ++i) {
        int lin = tid + i * 256;
        int rr  = lin >> 4;
        int c4  = (lin & 15) * 4;
        float4 v = *(const float4*)&W[(size_t)(r0 + rr) * NN + c0 + c4];
        float d[4] = {v.x, v.y, v.z, v.w};
        ushort4 ohi, olo;
        unsigned short* ph = (unsigned short*)&ohi;
        unsigned short* pl = (unsigned short*)&olo;
#pragma unroll
        for (int j = 0; j < 4; ++j) {
            float sv = 0.5f * (d[j] + T[c4 + j][rr]);
            if (r0 + rr == c0 + c4 + j) sv = 0.0f;
            unsigned short hi = f2bf(sv);
            ph[j] = hi;
            pl[j] = f2bf(sv - bf2f(hi));
        }
        const int n  = r0 + rr;            // W row == output column
        const int kg = c0 + c4;            // 4-aligned
        const int s16 = n >> 4, ln = n & 15;
        const int kc = kg >> 5, q = (kg & 31) >> 3, j0 = kg & 7;
        size_t off = (((size_t)s16 * 128 + kc) * 64 + q * 16 + ln) * 8 + j0;
        *(ushort4*)&Wfh[off] = ohi;        // 8B-aligned
        *(ushort4*)&Wfl[off] = olo;
    }
}

// ---------------------------------------------------------------------------
// Prologue 2: x0 = (1/beta)*log(g/(1-g)) (plain layout); g -> A-frag (hi,lo)
// ---------------------------------------------------------------------------
__global__ __launch_bounds__(256) void init_kernel(const float* __restrict__ g_in,
                                                   const float* __restrict__ beta,
                                                   float* __restrict__ x,
                                                   unsigned short* __restrict__ gfh,
                                                   unsigned short* __restrict__ gfl) {
    int idx = blockIdx.x * 256 + threadIdx.x;
    int r = idx >> 12, c = idx & (NN - 1);
    float g = g_in[idx];
    x[idx] = logf(g / (1.0f - g)) / beta[c];
    unsigned short hi = f2bf(g);
    unsigned short lo = f2bf(g - bf2f(hi));
    size_t off = (((size_t)(c >> 5) * 4 + (r >> 4)) * 64 + ((c & 31) >> 3) * 16 + (r & 15)) * 8 + (c & 7);
    gfh[off] = hi;
    gfl[off] = lo;
}

// ---------------------------------------------------------------------------
// Prologue 3: max_x = 50 / max(beta)
// ---------------------------------------------------------------------------
__global__ __launch_bounds__(256) void maxx_kernel(const float* __restrict__ beta,
                                                   float* __restrict__ out) {
    __shared__ float red[256];
    float m = -1e30f;
    for (int i = threadIdx.x; i < NN; i += 256) m = fmaxf(m, beta[i]);
    red[threadIdx.x] = m;
    __syncthreads();
    for (int s = 128; s > 0; s >>= 1) {
        if (threadIdx.x < s) red[threadIdx.x] = fmaxf(red[threadIdx.x], red[threadIdx.x + s]);
        __syncthreads();
    }
    if (threadIdx.x == 0) out[0] = 50.0f / red[0];
}

// ---------------------------------------------------------------------------
// Fused step kernel: ONE dispatch per step (was gemm + epi; kills the 8 MB
// P write + 8 MB P read round-trip and 200 epilogue launches).
// Grid 256 blocks = 256 strips of 16 output columns, each with FULL K=4096.
// 1024 threads = 16 waves; wave w owns K-slice [w*256, w*256+256) and all
// four 16-row m-subtiles (each A/B fragment loaded exactly once per block).
// 16-way K reduction via 65 KB LDS dump, then the same block applies the
// epilogue (b/alpha/clip/sigmoid, x update, next-step A-fragment writes).
// Kernel boundary = global barrier (in-kernel device sync costs 40-70 us/step
// on this 8-XCD part, per earlier rounds).
// ---------------------------------------------------------------------------
__global__ __launch_bounds__(1024, 1) void step_kernel(
    const unsigned short* __restrict__ gfh,
    const unsigned short* __restrict__ gfl,
    const unsigned short* __restrict__ Wfh,
    const unsigned short* __restrict__ Wfl,
    float* __restrict__ x,
    unsigned short* __restrict__ gfh_out,
    unsigned short* __restrict__ gfl_out,
    const float* __restrict__ bvec,
    const float* __restrict__ beta,
    const float* __restrict__ tau,
    const float* __restrict__ dt_ptr,
    const float* __restrict__ maxx_ptr,
    float* __restrict__ gout_f32)             // non-null on last step only
{
    __shared__ float sacc[16][16][65];        // [kslice][mq*4+rg][lane], +1 pad

    const int tid  = threadIdx.x;
    const int w    = tid >> 6;                // K-slice 0..15 (256 k each)
    const int lane = tid & 63;
    const int s16  = blockIdx.x;              // 16-col strip 0..255

    f32x4 acc[4] = {};                        // 4 m-subtiles x (16x16) frag

#pragma unroll 2
    for (int it = 0; it < 8; ++it) {
        const int kc = w * 8 + it;            // 32-wide K chunk index
        const size_t aBase = (size_t)kc * 2048 + lane * 8;                  // + mq*512
        const size_t bOff  = ((size_t)s16 * 128 + kc) * 512 + lane * 8;
        bf16x8 bh = *(const bf16x8*)&Wfh[bOff];
        bf16x8 bl = *(const bf16x8*)&Wfl[bOff];
        bf16x8 ah[4], al[4];
#pragma unroll
        for (int mq = 0; mq < 4; ++mq) {
            ah[mq] = *(const bf16x8*)&gfh[aBase + (size_t)mq * 512];
            al[mq] = *(const bf16x8*)&gfl[aBase + (size_t)mq * 512];
        }
#pragma unroll
        for (int mq = 0; mq < 4; ++mq) {
            acc[mq] = __builtin_amdgcn_mfma_f32_16x16x32_bf16(ah[mq], bh, acc[mq], 0, 0, 0);
            acc[mq] = __builtin_amdgcn_mfma_f32_16x16x32_bf16(al[mq], bh, acc[mq], 0, 0, 0);
            acc[mq] = __builtin_amdgcn_mfma_f32_16x16x32_bf16(ah[mq], bl, acc[mq], 0, 0, 0);
        }
    }

    // Dump all partials to LDS (lane-major -> conflict-free writes).
#pragma unroll
    for (int mq = 0; mq < 4; ++mq)
#pragma unroll
        for (int rg = 0; rg < 4; ++rg)
            sacc[w][mq * 4 + rg][lane] = acc[mq][rg];
    __syncthreads();

    // Epilogue: 256 threads, thread t -> (row m = t>>2, 4 cols starting qq*4).
    // C-frag layout: value(row16=q*4+rg, col=l16) sits at lane q*16+l16, reg rg.
    if (tid < 256) {
        const int m  = tid >> 2;
        const int qq = tid & 3;
        const int c0 = qq * 4;                // col within 16-wide strip
        const int n0 = s16 * 16 + c0;         // global col, 4-aligned
        const int mq = m >> 4;
        const int q  = (m & 15) >> 2;
        const int rg = m & 3;
        const int ridx = mq * 4 + rg;

        float sum[4];
#pragma unroll
        for (int jj = 0; jj < 4; ++jj) {
            float v = 0.0f;
#pragma unroll
            for (int kh = 0; kh < 16; ++kh)
                v += sacc[kh][ridx][q * 16 + c0 + jj];
            sum[jj] = v;
        }

        const float dt = *dt_ptr;
        const float mx = *maxx_ptr;
        float4 b0 = *(const float4*)&bvec[n0];
        float4 e0 = *(const float4*)&beta[n0];
        float4 t0 = *(const float4*)&tau[n0];
        float bb[4] = {b0.x, b0.y, b0.z, b0.w};
        float be[4] = {e0.x, e0.y, e0.z, e0.w};
        float tv[4] = {t0.x, t0.y, t0.z, t0.w};

        float* xp = &x[(size_t)m * NN + n0];
        float4 x0 = *(const float4*)xp;
        float xo[4] = {x0.x, x0.y, x0.z, x0.w};

        float gg[4];
        unsigned short vh[4], vl[4];
#pragma unroll
        for (int j = 0; j < 4; ++j) {
            const float al = dt / tv[j];
            float xn = al * (sum[j] + bb[j]) + (1.0f - al) * xo[j];
            xn = fminf(fmaxf(xn, -mx), mx);
            float g = 1.0f / (1.0f + __expf(-be[j] * xn));
            xo[j] = xn;
            gg[j] = g;
            unsigned short hi = f2bf(g);
            vh[j] = hi;
            vl[j] = f2bf(g - bf2f(hi));
        }
        *(float4*)xp = {xo[0], xo[1], xo[2], xo[3]};

        // A-fragment address for (m, kg = n0..n0+3): j = n0&7 .. +3 contiguous,
        // 8B-aligned since n0 % 4 == 0.
        size_t off = (((size_t)(n0 >> 5) * 4 + (m >> 4)) * 64 + ((n0 & 31) >> 3) * 16 + (m & 15)) * 8 + (n0 & 7);
        *(ushort4*)&gfh_out[off] = {vh[0], vh[1], vh[2], vh[3]};
        *(ushort4*)&gfl_out[off] = {vl[0], vl[1], vl[2], vl[3]};

        if (gout_f32)
            *(float4*)&gout_f32[(size_t)m * NN + n0] = {gg[0], gg[1], gg[2], gg[3]};
    }
}

// ---------------------------------------------------------------------------
extern "C" void kernel_launch(void* const* d_in, const int* in_sizes, int n_in,
                              void* d_out, int out_size, void* d_ws, size_t ws_size,
                              hipStream_t stream) {
    const float* state_g = (const float*)d_in[0];
    const float* W       = (const float*)d_in[1];
    const float* b       = (const float*)d_in[2];
    const float* beta    = (const float*)d_in[3];
    const float* tau     = (const float*)d_in[4];
    const float* dt      = (const float*)d_in[5];
    float* out = (float*)d_out;

    char* ws = (char*)d_ws;
    const size_t WH = (size_t)KK * NN * 2;    // 32 MB per W-frag array
    const size_t XB = (size_t)MM * NN * 4;    // 1 MB
    const size_t GB = (size_t)MM * NN * 2;    // 512 KB per g-frag array
    unsigned short* Wfh = (unsigned short*)ws;
    unsigned short* Wfl = (unsigned short*)(ws + WH);
    float*          x   = (float*)(ws + 2 * WH);
    unsigned short* g0h = (unsigned short*)(ws + 2 * WH + XB);
    unsigned short* g0l = (unsigned short*)(ws + 2 * WH + XB + GB);
    unsigned short* g1h = (unsigned short*)(ws + 2 * WH + XB + 2 * GB);
    unsigned short* g1l = (unsigned short*)(ws + 2 * WH + XB + 3 * GB);
    float*          mxp = (float*)(ws + 2 * WH + XB + 4 * GB);

    symm_kernel<<<dim3(64, 64), 256, 0, stream>>>(W, Wfh, Wfl);
    init_kernel<<<(MM * NN) / 256, 256, 0, stream>>>(state_g, beta, x, g0h, g0l);
    maxx_kernel<<<1, 256, 0, stream>>>(beta, mxp);

    unsigned short *gih = g0h, *gil = g0l, *goh = g1h, *gol = g1l;
    for (int st = 0; st < NSTEP; ++st) {
        float* of = (st == NSTEP - 1) ? out : nullptr;
        step_kernel<<<256, 1024, 0, stream>>>(gih, gil, Wfh, Wfl, x,
                                              goh, gol, b, beta, tau, dt, mxp, of);
        unsigned short* tp;
        tp = gih; gih = goh; goh = tp;
        tp = gil; gil = gol; gol = tp;
    }
}

// Round 5
// 3661.342 us; speedup vs baseline: 1.1507x; 1.1507x over previous
//
#include <hip/hip_runtime.h>
#include <hip/hip_bf16.h>

// Problem constants (fixed shapes per reference setup_inputs; n_step = 200).
#define MM 64
#define NN 4096
#define KK 4096
#define NSTEP 200

typedef __bf16 bf16x8 __attribute__((ext_vector_type(8)));
typedef float  f32x4  __attribute__((ext_vector_type(4)));

static __device__ __forceinline__ unsigned short f2bf(float f) {
    __hip_bfloat16 h = __float2bfloat16(f);
    return __builtin_bit_cast(unsigned short, h);
}
static __device__ __forceinline__ float bf2f(unsigned short u) {
    __hip_bfloat16 h = __builtin_bit_cast(__hip_bfloat16, u);
    return __bfloat162float(h);
}

// Fragment layouts (mfma_f32_16x16x32_bf16, m89 mapping:
//   frag[lane=q*16+l16][j] = Mat[row16=l16][k=q*8+j]):
// A (g):  addr(m,kg) = ((kc*4 + (m>>4))*64 + q*16 + (m&15))*8 + j
// B (W):  addr(n,kg) = (((n>>4)*128 + kc)*64 + q*16 + (n&15))*8 + j

// ---------------------------------------------------------------------------
// Prologue 1: s = 0.5*(W[n][k]+W[k][n]), diag zero; (hi,lo) bf16 split,
// scattered into B-fragment order. 64x64 tiles, LDS transpose.
// ---------------------------------------------------------------------------
__global__ __launch_bounds__(256) void symm_kernel(const float* __restrict__ W,
                                                   unsigned short* __restrict__ Wfh,
                                                   unsigned short* __restrict__ Wfl) {
    __shared__ float T[64][65];
    const int tid = threadIdx.x;
    const int r0 = blockIdx.y * 64, c0 = blockIdx.x * 64;
#pragma unroll
    for (int i = 0; i < 4; ++i) {
        int lin = tid + i * 256;
        int cc  = lin >> 4;
        int r4  = (lin & 15) * 4;
        float4 v = *(const float4*)&W[(size_t)(c0 + cc) * NN + r0 + r4];
        T[cc][r4 + 0] = v.x; T[cc][r4 + 1] = v.y;
        T[cc][r4 + 2] = v.z; T[cc][r4 + 3] = v.w;
    }
    __syncthreads();
#pragma unroll
    for (int i = 0; i < 4; ++i) {
        int lin = tid + i * 256;
        int rr  = lin >> 4;
        int c4  = (lin & 15) * 4;
        float4 v = *(const float4*)&W[(size_t)(r0 + rr) * NN + c0 + c4];
        float d[4] = {v.x, v.y, v.z, v.w};
        ushort4 ohi, olo;
        unsigned short* ph = (unsigned short*)&ohi;
        unsigned short* pl = (unsigned short*)&olo;
#pragma unroll
        for (int j = 0; j < 4; ++j) {
            float sv = 0.5f * (d[j] + T[c4 + j][rr]);
            if (r0 + rr == c0 + c4 + j) sv = 0.0f;
            unsigned short hi = f2bf(sv);
            ph[j] = hi;
            pl[j] = f2bf(sv - bf2f(hi));
        }
        const int n  = r0 + rr;            // W row == output column
        const int kg = c0 + c4;            // 4-aligned
        const int s16 = n >> 4, ln = n & 15;
        const int kc = kg >> 5, q = (kg & 31) >> 3, j0 = kg & 7;
        size_t off = (((size_t)s16 * 128 + kc) * 64 + q * 16 + ln) * 8 + j0;
        *(ushort4*)&Wfh[off] = ohi;        // 8B-aligned
        *(ushort4*)&Wfl[off] = olo;
    }
}

// ---------------------------------------------------------------------------
// Prologue 2: x0 = (1/beta)*log(g/(1-g)) (plain layout); g -> A-frag (hi,lo)
// ---------------------------------------------------------------------------
__global__ __launch_bounds__(256) void init_kernel(const float* __restrict__ g_in,
                                                   const float* __restrict__ beta,
                                                   float* __restrict__ x,
                                                   unsigned short* __restrict__ gfh,
                                                   unsigned short* __restrict__ gfl) {
    int idx = blockIdx.x * 256 + threadIdx.x;
    int r = idx >> 12, c = idx & (NN - 1);
    float g = g_in[idx];
    x[idx] = logf(g / (1.0f - g)) / beta[c];
    unsigned short hi = f2bf(g);
    unsigned short lo = f2bf(g - bf2f(hi));
    size_t off = (((size_t)(c >> 5) * 4 + (r >> 4)) * 64 + ((c & 31) >> 3) * 16 + (r & 15)) * 8 + (c & 7);
    gfh[off] = hi;
    gfl[off] = lo;
}

// ---------------------------------------------------------------------------
// Prologue 3: max_x = 50 / max(beta)
// ---------------------------------------------------------------------------
__global__ __launch_bounds__(256) void maxx_kernel(const float* __restrict__ beta,
                                                   float* __restrict__ out) {
    __shared__ float red[256];
    float m = -1e30f;
    for (int i = threadIdx.x; i < NN; i += 256) m = fmaxf(m, beta[i]);
    red[threadIdx.x] = m;
    __syncthreads();
    for (int s = 128; s > 0; s >>= 1) {
        if (threadIdx.x < s) red[threadIdx.x] = fmaxf(red[threadIdx.x], red[threadIdx.x + s]);
        __syncthreads();
    }
    if (threadIdx.x == 0) out[0] = 50.0f / red[0];
}

// ---------------------------------------------------------------------------
// Fused step kernel v2. Grid 256 blocks = 256 strips of 16 output columns,
// full K=4096 per block; 16 waves, wave w owns K-slice [w*256, w*256+256).
// v2 changes vs v1 (which measured 20.8 us/step vs 18.8 baseline):
//  - K-loop fully unrolled (was unroll 2): compiler can hoist next-iter
//    loads over current MFMAs across the whole body (128-VGPR budget).
//  - Epilogue on ALL 1024 threads (64 rows x 16 cols = 1 output/thread);
//    v1 used 256 threads (3/4 of CU idled in the tail).
//  - Epilogue global loads issued before the LDS dump + barrier.
// Known cost kept: g-frag replication x256 blocks = 256 MB/step via L2
// (floor ~7.4 us/step) — next candidate attacks this via smaller g stream.
// ---------------------------------------------------------------------------
__global__ __launch_bounds__(1024, 1) void step_kernel(
    const unsigned short* __restrict__ gfh,
    const unsigned short* __restrict__ gfl,
    const unsigned short* __restrict__ Wfh,
    const unsigned short* __restrict__ Wfl,
    float* __restrict__ x,
    unsigned short* __restrict__ gfh_out,
    unsigned short* __restrict__ gfl_out,
    const float* __restrict__ bvec,
    const float* __restrict__ beta,
    const float* __restrict__ tau,
    const float* __restrict__ dt_ptr,
    const float* __restrict__ maxx_ptr,
    float* __restrict__ gout_f32)             // non-null on last step only
{
    __shared__ float sacc[16][16][65];        // [kslice][mq*4+rg][lane], +1 pad

    const int tid  = threadIdx.x;
    const int w    = tid >> 6;                // K-slice 0..15 (256 k each)
    const int lane = tid & 63;
    const int s16  = blockIdx.x;              // 16-col strip 0..255

    f32x4 acc[4] = {};                        // 4 m-subtiles x (16x16) frag

#pragma unroll
    for (int it = 0; it < 8; ++it) {
        const int kc = w * 8 + it;            // 32-wide K chunk index
        const size_t aBase = (size_t)kc * 2048 + lane * 8;                  // + mq*512
        const size_t bOff  = ((size_t)s16 * 128 + kc) * 512 + lane * 8;
        bf16x8 bh = *(const bf16x8*)&Wfh[bOff];
        bf16x8 bl = *(const bf16x8*)&Wfl[bOff];
        bf16x8 ah[4], al[4];
#pragma unroll
        for (int mq = 0; mq < 4; ++mq) {
            ah[mq] = *(const bf16x8*)&gfh[aBase + (size_t)mq * 512];
            al[mq] = *(const bf16x8*)&gfl[aBase + (size_t)mq * 512];
        }
#pragma unroll
        for (int mq = 0; mq < 4; ++mq) {
            acc[mq] = __builtin_amdgcn_mfma_f32_16x16x32_bf16(ah[mq], bh, acc[mq], 0, 0, 0);
            acc[mq] = __builtin_amdgcn_mfma_f32_16x16x32_bf16(al[mq], bh, acc[mq], 0, 0, 0);
            acc[mq] = __builtin_amdgcn_mfma_f32_16x16x32_bf16(ah[mq], bl, acc[mq], 0, 0, 0);
        }
    }

    // Epilogue operand loads for THIS thread's output (m = tid>>4, c = tid&15):
    // issue before the LDS dump so the latency hides under dump + barrier.
    const int m  = tid >> 4;                  // batch row 0..63
    const int c  = tid & 15;                  // col within strip
    const int n  = s16 * 16 + c;              // global col
    const float dt = *dt_ptr;
    const float mx = *maxx_ptr;
    const float bb = bvec[n];
    const float be = beta[n];
    const float tv = tau[n];
    float* xp = &x[(size_t)m * NN + n];
    const float xold = *xp;

    // Dump all partials to LDS (lane-major -> 2-way aliasing only, free).
#pragma unroll
    for (int mq = 0; mq < 4; ++mq)
#pragma unroll
        for (int rg = 0; rg < 4; ++rg)
            sacc[w][mq * 4 + rg][lane] = acc[mq][rg];
    __syncthreads();

    // Epilogue: ALL 1024 threads, 1 output each.
    // C-frag layout: value(row16=q*4+rg, col=l16) at lane q*16+l16, reg rg.
    {
        const int mq = m >> 4;
        const int q  = (m & 15) >> 2;
        const int rg = m & 3;
        const int ridx = mq * 4 + rg;

        float sum = 0.0f;
#pragma unroll
        for (int kh = 0; kh < 16; ++kh)
            sum += sacc[kh][ridx][q * 16 + c];

        const float al = dt / tv;
        float xn = al * (sum + bb) + (1.0f - al) * xold;
        xn = fminf(fmaxf(xn, -mx), mx);
        float g = 1.0f / (1.0f + __expf(-be * xn));
        *xp = xn;

        unsigned short hi = f2bf(g);
        unsigned short lo = f2bf(g - bf2f(hi));
        // A-fragment address for (m, kg = n):
        size_t off = (((size_t)(n >> 5) * 4 + (m >> 4)) * 64 + ((n & 31) >> 3) * 16 + (m & 15)) * 8 + (n & 7);
        gfh_out[off] = hi;
        gfl_out[off] = lo;

        if (gout_f32)
            gout_f32[(size_t)m * NN + n] = g;
    }
}

// ---------------------------------------------------------------------------
extern "C" void kernel_launch(void* const* d_in, const int* in_sizes, int n_in,
                              void* d_out, int out_size, void* d_ws, size_t ws_size,
                              hipStream_t stream) {
    const float* state_g = (const float*)d_in[0];
    const float* W       = (const float*)d_in[1];
    const float* b       = (const float*)d_in[2];
    const float* beta    = (const float*)d_in[3];
    const float* tau     = (const float*)d_in[4];
    const float* dt      = (const float*)d_in[5];
    float* out = (float*)d_out;

    char* ws = (char*)d_ws;
    const size_t WH = (size_t)KK * NN * 2;    // 32 MB per W-frag array
    const size_t XB = (size_t)MM * NN * 4;    // 1 MB
    const size_t GB = (size_t)MM * NN * 2;    // 512 KB per g-frag array
    unsigned short* Wfh = (unsigned short*)ws;
    unsigned short* Wfl = (unsigned short*)(ws + WH);
    float*          x   = (float*)(ws + 2 * WH);
    unsigned short* g0h = (unsigned short*)(ws + 2 * WH + XB);
    unsigned short* g0l = (unsigned short*)(ws + 2 * WH + XB + GB);
    unsigned short* g1h = (unsigned short*)(ws + 2 * WH + XB + 2 * GB);
    unsigned short* g1l = (unsigned short*)(ws + 2 * WH + XB + 3 * GB);
    float*          mxp = (float*)(ws + 2 * WH + XB + 4 * GB);

    symm_kernel<<<dim3(64, 64), 256, 0, stream>>>(W, Wfh, Wfl);
    init_kernel<<<(MM * NN) / 256, 256, 0, stream>>>(state_g, beta, x, g0h, g0l);
    maxx_kernel<<<1, 256, 0, stream>>>(beta, mxp);

    unsigned short *gih = g0h, *gil = g0l, *goh = g1h, *gol = g1l;
    for (int st = 0; st < NSTEP; ++st) {
        float* of = (st == NSTEP - 1) ? out : nullptr;
        step_kernel<<<256, 1024, 0, stream>>>(gih, gil, Wfh, Wfl, x,
                                              goh, gol, b, beta, tau, dt, mxp, of);
        unsigned short* tp;
        tp = gih; gih = goh; goh = tp;
        tp = gil; gil = gol; gol = tp;
    }
}